// Round 6
// baseline (2473.497 us; speedup 1.0000x reference)
//
#include <hip/hip_runtime.h>
#include <hip/hip_bf16.h>

typedef unsigned short ushortT;
typedef __attribute__((ext_vector_type(8))) short short8;
typedef __attribute__((ext_vector_type(4))) float f32x4;

#define CIN 512
#define COUTC 512
#define HIDC 512
#define BATCH 16
#define HDIM 64
#define WDIM 64
#define HP 66   // padded spatial

// ws layout (bytes):
//   s     @ 0        : 16*512*4   = 32768
//   d     @ 32768    : 16*512*4   = 32768
//   w2    @ 65536    : 512*512*4  = 1048576
//   wbt   @ 1114112  : 9*512*512*2 = 4718592   (bf16, tap-major [t][o][i])
//   xpad  @ 5832704  : 16*66*66*512*2 = 71368704 (bf16 NHWC, zero-padded)

__device__ __forceinline__ unsigned short f2bf(float f) {
    __hip_bfloat16 h = __float2bfloat16(f);
    return __builtin_bit_cast(unsigned short, h);
}

__device__ __forceinline__ void gload16(const ushortT* g, ushortT* l) {
    __builtin_amdgcn_global_load_lds(
        (const __attribute__((address_space(1))) void*)g,
        (__attribute__((address_space(3))) void*)l, 16, 0, 0);
}

// s[b][i] = (y[b,:] . mod_w[i,:]) / sqrt(512) + mod_b[i] + 1   — one wave per (b,i)
__global__ void k_style(const float* __restrict__ y, const float* __restrict__ mw,
                        const float* __restrict__ mb, float* __restrict__ s) {
    int lane = threadIdx.x & 63;
    int wid = blockIdx.x * 4 + (threadIdx.x >> 6);   // 0..8191
    int b = wid >> 9, i = wid & 511;
    int h0 = lane * 8;
    float4 ya = *(const float4*)(y + b * HIDC + h0);
    float4 yb = *(const float4*)(y + b * HIDC + h0 + 4);
    float4 wa = *(const float4*)(mw + (size_t)i * HIDC + h0);
    float4 wb = *(const float4*)(mw + (size_t)i * HIDC + h0 + 4);
    float v = ya.x*wa.x + ya.y*wa.y + ya.z*wa.z + ya.w*wa.w
            + yb.x*wb.x + yb.y*wb.y + yb.z*wb.z + yb.w*wb.w;
    #pragma unroll
    for (int off = 32; off > 0; off >>= 1) v += __shfl_down(v, off);
    if (lane == 0) s[wid] = v * 0.04419417382415922f + mb[i] + 1.0f;
}

// wbt[k][o][i] = bf16(w[o][i][k] * coef);  w2[o][i] = sum_k (w*coef)^2
__global__ void k_prepw(const float* __restrict__ w, float* __restrict__ w2,
                        ushortT* __restrict__ wbt) {
    int t = blockIdx.x * 256 + threadIdx.x;   // o*512 + i
    const float* wp = w + (size_t)t * 9;
    const float coef = 0.014731391274719739f; // 1/sqrt(4608)
    float sum = 0.f;
    #pragma unroll
    for (int k = 0; k < 9; ++k) {
        float v = wp[k] * coef;
        sum += v * v;
        wbt[(size_t)k * (COUTC * CIN) + t] = f2bf(v);
    }
    w2[t] = sum;
}

// d[b][o] = rsqrt(sum_i w2[o][i] * s[b][i]^2 + 1e-8)  — one wave per (b,o)
__global__ void k_demod(const float* __restrict__ w2, const float* __restrict__ s,
                        float* __restrict__ d) {
    int lane = threadIdx.x & 63;
    int wid = blockIdx.x * 4 + (threadIdx.x >> 6);   // 0..8191
    int b = wid >> 9, o = wid & 511;
    int i0 = lane * 8;
    float4 wa = *(const float4*)(w2 + (size_t)o * CIN + i0);
    float4 wb = *(const float4*)(w2 + (size_t)o * CIN + i0 + 4);
    float4 sa = *(const float4*)(s + b * CIN + i0);
    float4 sb = *(const float4*)(s + b * CIN + i0 + 4);
    float v = wa.x*sa.x*sa.x + wa.y*sa.y*sa.y + wa.z*sa.z*sa.z + wa.w*sa.w*sa.w
            + wb.x*sb.x*sb.x + wb.y*sb.y*sb.y + wb.z*sb.z*sb.z + wb.w*sb.w*sb.w;
    #pragma unroll
    for (int off = 32; off > 0; off >>= 1) v += __shfl_down(v, off);
    if (lane == 0) d[wid] = rsqrtf(v + 1e-8f);
}

// xpad[b][row][col][ch] = bf16(x[b][ch][row-1][col-1] * s[b][ch]), zero border.
__global__ void k_pad(const float* __restrict__ x, const float* __restrict__ s,
                      ushortT* __restrict__ xpad) {
    __shared__ float tilef[64 * 129];   // [w 0..63][ch 0..127], 33 KB
    int bid = blockIdx.x;
    int cchunk = bid & 3;               // 4 chunks of 128 ch
    int rem = bid >> 2;
    int prow = rem % HP;
    int b = rem / HP;
    int tid = threadIdx.x;
    size_t rowbase = (((size_t)b * HP + prow) * HP) * CIN + cchunk * 128;
    if (prow == 0 || prow == HP - 1) {
        short8 z = {};
        for (int q = tid; q < HP * 16; q += 256) {   // 66 cols x 16 subs
            int col = q >> 4, sub = q & 15;
            *(short8*)(xpad + rowbase + (size_t)col * CIN + sub * 8) = z;
        }
        return;
    }
    int xr = prow - 1;
    int u = tid & 15;           // w quad
    int cbase = tid >> 4;       // 0..15
    #pragma unroll
    for (int it = 0; it < 8; ++it) {
        int c = cbase + it * 16;                     // 0..127
        int ch = cchunk * 128 + c;
        float4 v = *(const float4*)(x + (((size_t)b * CIN + ch) * HDIM + xr) * WDIM + u * 4);
        float sv = s[b * CIN + ch];
        tilef[(u * 4 + 0) * 129 + c] = v.x * sv;
        tilef[(u * 4 + 1) * 129 + c] = v.y * sv;
        tilef[(u * 4 + 2) * 129 + c] = v.z * sv;
        tilef[(u * 4 + 3) * 129 + c] = v.w * sv;
    }
    __syncthreads();
    #pragma unroll
    for (int it = 0; it < 4; ++it) {
        int q = it * 256 + tid;                      // 0..1023
        int col = 1 + (q >> 4);                      // 1..64
        int sub = q & 15;                            // ch octet
        const float* tr = tilef + (col - 1) * 129 + sub * 8;
        short8 o;
        #pragma unroll
        for (int r = 0; r < 8; ++r) o[r] = (short)f2bf(tr[r]);
        *(short8*)(xpad + rowbase + (size_t)col * CIN + sub * 8) = o;
    }
    if (tid < 32) {
        short8 z = {};
        int bcol = (tid < 16) ? 0 : (HP - 1);
        *(short8*)(xpad + rowbase + (size_t)bcol * CIN + (tid & 15) * 8) = z;
    }
}

// Implicit-GEMM conv, 256x256 tile, BK=64, SINGLE-buffered LDS (64 KiB/block)
// => 2 blocks/CU. Rationale (R5 post-mortem): with 1 block/CU the 8 waves are
// barrier-locked into one phase, so the LDS pipe (~139 us demand) and MFMA pipe
// (~124 us) strictly serialize (~300 us measured). Two co-resident blocks with
// independent barriers interleave the pipes (m114 implicit overlap).
// Per K-step: stage all 8 chunks -> vmcnt(0)+barrier -> the PROVEN 4-phase
// double-barrier compute (R3: per-phase barriers are load-bearing; R5: only the
// 8-slot/128B-row XOR swizzle is bank-conflict-free — both kept verbatim).
#define MFMA_CLUSTER(MH) do { \
    __builtin_amdgcn_s_setprio(1); \
    _Pragma("unroll") for (int m_ = 0; m_ < 4; ++m_) { \
        _Pragma("unroll") for (int n_ = 0; n_ < 4; ++n_) \
            acc[(MH)*4 + m_][n_] = __builtin_amdgcn_mfma_f32_16x16x32_bf16( \
                af[m_], bf[n_], acc[(MH)*4 + m_][n_], 0, 0, 0); } \
    __builtin_amdgcn_s_setprio(0); \
} while (0)

#define DS_A(MH, KH) do { \
    _Pragma("unroll") for (int m_ = 0; m_ < 4; ++m_) { \
        int row_ = wave_m * 128 + (MH)*64 + m_*16 + l15; \
        af[m_] = *(const short8*)(As + row_*64 + ((((KH)*4 + quad) ^ (row_ & 7)) * 8)); \
    } } while (0)

#define DS_B(KH) do { \
    _Pragma("unroll") for (int n_ = 0; n_ < 4; ++n_) { \
        int row_ = wave_n * 64 + n_*16 + l15; \
        bf[n_] = *(const short8*)(Bs + row_*64 + ((((KH)*4 + quad) ^ (row_ & 7)) * 8)); \
    } } while (0)

__global__ __launch_bounds__(512, 4) void k_conv(
    const ushortT* __restrict__ wbt, const ushortT* __restrict__ xpad,
    const float* __restrict__ dcoef, const float* __restrict__ bias,
    const float* __restrict__ noise, const float* __restrict__ nscp,
    float* __restrict__ out)
{
    extern __shared__ __align__(16) ushortT smem[];   // 65536 B
    ushortT* As = smem;            // 32 KiB: A tile 256 x 64
    ushortT* Bs = smem + 16384;    // 32 KiB: B tile 256 x 64

    int tid = threadIdx.x;
    int lane = tid & 63;
    int wave = tid >> 6;          // 0..7
    int wave_m = wave >> 2;       // 0..1  (128 couts each)
    int wave_n = wave & 3;        // 0..3  (64 pos each)
    int l15 = lane & 15;
    int quad = lane >> 4;

    // XCD-aware swizzle: nwg=512, 8 XCDs, 64 consecutive wgids per XCD.
    int bid = blockIdx.x;
    int wg = (bid & 7) * 64 + (bid >> 3);
    int mtile = wg >> 8;          // 0..1
    int ntile = wg & 255;         // 0..255
    int b = ntile >> 4;           // image
    int h0 = (ntile & 15) << 2;   // 4 output rows h0..h0+3
    int cout0 = mtile << 8;       // 256 couts

    // staging: per K-step, A tile = 256 rows x 64 ch x 2B = 2048 x 16B chunks,
    // 4 calls x 512 threads; same for B. chunk a: row=a>>3, slot=a&7,
    // global sub = slot ^ (row&7)  (involution with the DS_ read swizzle).
    unsigned aoff[4], boff[4], dstE[4];
    #pragma unroll
    for (int ca = 0; ca < 4; ++ca) {
        int a = ca * 512 + tid;
        int row = a >> 3;
        int sub = (a & 7) ^ (row & 7);
        aoff[ca] = (unsigned)((cout0 + row) * CIN + sub * 8);
        int prow = row >> 6;       // 0..3
        int pcol = row & 63;
        boff[ca] = (unsigned)((((b * HP) + h0 + prow) * HP + pcol) * CIN + sub * 8);
        dstE[ca] = (unsigned)(ca * 4096 + wave * 512);   // wave-uniform LDS base (elems)
    }

    f32x4 acc[8][4] = {};

    // ---- main loop: 72 K-steps (9 taps x 8 chunks of 64 ch)
    for (int ks = 0; ks < 72; ++ks) {
        int tn = ks >> 3, cc = ks & 7;
        const ushortT* Asrc = wbt + (size_t)tn * (COUTC * CIN) + cc * 64;
        const ushortT* Bsrc = xpad + ((size_t)(tn / 3) * HP + (tn % 3)) * CIN + cc * 64;

        // stage this K-step (buffer free: previous step's closing barrier
        // guarantees all waves' reads completed)
        #pragma unroll
        for (int ca = 0; ca < 4; ++ca) {
            gload16(Asrc + aoff[ca], As + dstE[ca]);
            gload16(Bsrc + boff[ca], Bs + dstE[ca]);
        }
        asm volatile("s_waitcnt vmcnt(0)" ::: "memory");
        __builtin_amdgcn_s_barrier();

        short8 af[4], bf[4];

        // ---- phase 0: kh=0, mh=0
        DS_B(0);
        DS_A(0, 0);
        __builtin_amdgcn_s_barrier();
        asm volatile("s_waitcnt lgkmcnt(0)");
        MFMA_CLUSTER(0);
        __builtin_amdgcn_s_barrier();

        // ---- phase 1: kh=0, mh=1
        DS_A(1, 0);
        __builtin_amdgcn_s_barrier();
        asm volatile("s_waitcnt lgkmcnt(0)");
        MFMA_CLUSTER(1);
        __builtin_amdgcn_s_barrier();

        // ---- phase 2: kh=1, mh=0
        DS_B(1);
        DS_A(0, 1);
        __builtin_amdgcn_s_barrier();
        asm volatile("s_waitcnt lgkmcnt(0)");
        MFMA_CLUSTER(0);
        __builtin_amdgcn_s_barrier();

        // ---- phase 3: kh=1, mh=1
        DS_A(1, 1);
        __builtin_amdgcn_s_barrier();
        asm volatile("s_waitcnt lgkmcnt(0)");
        MFMA_CLUSTER(1);
        __builtin_amdgcn_s_barrier();
    }

    // ---- epilogue: out = acc * d[b,o] + noise*nscale + bias
    float ns = nscp[0];
    int col = lane & 15, rq = lane >> 4;
    #pragma unroll
    for (int nj = 0; nj < 4; ++nj) {
        int pos = wave_n * 64 + nj * 16 + col;
        int hh = h0 + (pos >> 6), ww = pos & 63;
        float nz = noise[((size_t)b << 12) + (hh << 6) + ww] * ns;
        #pragma unroll
        for (int mi = 0; mi < 8; ++mi) {
            int coutb = cout0 + wave_m * 128 + mi * 16 + rq * 4;
            f32x4 dv = *(const f32x4*)(dcoef + b * COUTC + coutb);
            f32x4 bv = *(const f32x4*)(bias + coutb);
            f32x4 a = acc[mi][nj];
            #pragma unroll
            for (int r = 0; r < 4; ++r) {
                out[(((size_t)(b * COUTC + coutb + r)) << 12) + (hh << 6) + ww]
                    = a[r] * dv[r] + nz + bv[r];
            }
        }
    }
}

extern "C" void kernel_launch(void* const* d_in, const int* in_sizes, int n_in,
                              void* d_out, int out_size, void* d_ws, size_t ws_size,
                              hipStream_t stream) {
    const float* x      = (const float*)d_in[0];
    const float* y      = (const float*)d_in[1];
    const float* noise  = (const float*)d_in[2];
    const float* weight = (const float*)d_in[3];
    const float* bias   = (const float*)d_in[4];
    const float* mod_w  = (const float*)d_in[5];
    const float* mod_b  = (const float*)d_in[6];
    const float* nsc    = (const float*)d_in[7];
    float* out = (float*)d_out;

    char* ws = (char*)d_ws;
    float*   s     = (float*)(ws);
    float*   dcoef = (float*)(ws + 32768);
    float*   w2    = (float*)(ws + 65536);
    ushortT* wbt   = (ushortT*)(ws + 1114112);
    ushortT* xpad  = (ushortT*)(ws + 5832704);

    static bool attr_done = false;
    if (!attr_done) {
        (void)hipFuncSetAttribute(reinterpret_cast<const void*>(k_conv),
                                  hipFuncAttributeMaxDynamicSharedMemorySize, 65536);
        attr_done = true;
    }

    k_style<<<dim3(2048), dim3(256), 0, stream>>>(y, mod_w, mod_b, s);
    k_prepw<<<dim3(1024), dim3(256), 0, stream>>>(weight, w2, wbt);
    k_demod<<<dim3(2048), dim3(256), 0, stream>>>(w2, s, dcoef);
    k_pad<<<dim3(BATCH * HP * 4), dim3(256), 0, stream>>>(x, s, xpad);
    k_conv<<<dim3(512), dim3(512), 65536, stream>>>(wbt, xpad, dcoef, bias, noise, nsc, out);
}

// Round 7
// 510.827 us; speedup vs baseline: 4.8421x; 4.8421x over previous
//
#include <hip/hip_runtime.h>
#include <hip/hip_bf16.h>

typedef unsigned short ushortT;
typedef __attribute__((ext_vector_type(8))) short short8;
typedef __attribute__((ext_vector_type(4))) float f32x4;

#define CIN 512
#define COUTC 512
#define HIDC 512
#define BATCH 16
#define HDIM 64
#define WDIM 64
#define HP 66   // padded spatial

// ws layout (bytes):
//   s     @ 0        : 16*512*4   = 32768
//   d     @ 32768    : 16*512*4   = 32768
//   w2    @ 65536    : 512*512*4  = 1048576
//   wbt   @ 1114112  : 9*512*512*2 = 4718592   (bf16, tap-major [t][o][i])
//   xpad  @ 5832704  : 16*66*66*512*2 = 71368704 (bf16 NHWC, zero-padded)

__device__ __forceinline__ unsigned short f2bf(float f) {
    __hip_bfloat16 h = __float2bfloat16(f);
    return __builtin_bit_cast(unsigned short, h);
}

__device__ __forceinline__ void gload16(const ushortT* g, ushortT* l) {
    __builtin_amdgcn_global_load_lds(
        (const __attribute__((address_space(1))) void*)g,
        (__attribute__((address_space(3))) void*)l, 16, 0, 0);
}

// s[b][i] = (y[b,:] . mod_w[i,:]) / sqrt(512) + mod_b[i] + 1   — one wave per (b,i)
__global__ void k_style(const float* __restrict__ y, const float* __restrict__ mw,
                        const float* __restrict__ mb, float* __restrict__ s) {
    int lane = threadIdx.x & 63;
    int wid = blockIdx.x * 4 + (threadIdx.x >> 6);   // 0..8191
    int b = wid >> 9, i = wid & 511;
    int h0 = lane * 8;
    float4 ya = *(const float4*)(y + b * HIDC + h0);
    float4 yb = *(const float4*)(y + b * HIDC + h0 + 4);
    float4 wa = *(const float4*)(mw + (size_t)i * HIDC + h0);
    float4 wb = *(const float4*)(mw + (size_t)i * HIDC + h0 + 4);
    float v = ya.x*wa.x + ya.y*wa.y + ya.z*wa.z + ya.w*wa.w
            + yb.x*wb.x + yb.y*wb.y + yb.z*wb.z + yb.w*wb.w;
    #pragma unroll
    for (int off = 32; off > 0; off >>= 1) v += __shfl_down(v, off);
    if (lane == 0) s[wid] = v * 0.04419417382415922f + mb[i] + 1.0f;
}

// wbt[k][o][i] = bf16(w[o][i][k] * coef);  w2[o][i] = sum_k (w*coef)^2
__global__ void k_prepw(const float* __restrict__ w, float* __restrict__ w2,
                        ushortT* __restrict__ wbt) {
    int t = blockIdx.x * 256 + threadIdx.x;   // o*512 + i
    const float* wp = w + (size_t)t * 9;
    const float coef = 0.014731391274719739f; // 1/sqrt(4608)
    float sum = 0.f;
    #pragma unroll
    for (int k = 0; k < 9; ++k) {
        float v = wp[k] * coef;
        sum += v * v;
        wbt[(size_t)k * (COUTC * CIN) + t] = f2bf(v);
    }
    w2[t] = sum;
}

// d[b][o] = rsqrt(sum_i w2[o][i] * s[b][i]^2 + 1e-8)  — one wave per (b,o)
__global__ void k_demod(const float* __restrict__ w2, const float* __restrict__ s,
                        float* __restrict__ d) {
    int lane = threadIdx.x & 63;
    int wid = blockIdx.x * 4 + (threadIdx.x >> 6);   // 0..8191
    int b = wid >> 9, o = wid & 511;
    int i0 = lane * 8;
    float4 wa = *(const float4*)(w2 + (size_t)o * CIN + i0);
    float4 wb = *(const float4*)(w2 + (size_t)o * CIN + i0 + 4);
    float4 sa = *(const float4*)(s + b * CIN + i0);
    float4 sb = *(const float4*)(s + b * CIN + i0 + 4);
    float v = wa.x*sa.x*sa.x + wa.y*sa.y*sa.y + wa.z*sa.z*sa.z + wa.w*sa.w*sa.w
            + wb.x*sb.x*sb.x + wb.y*sb.y*sb.y + wb.z*sb.z*sb.z + wb.w*sb.w*sb.w;
    #pragma unroll
    for (int off = 32; off > 0; off >>= 1) v += __shfl_down(v, off);
    if (lane == 0) d[wid] = rsqrtf(v + 1e-8f);
}

// xpad[b][row][col][ch] = bf16(x[b][ch][row-1][col-1] * s[b][ch]), zero border.
__global__ void k_pad(const float* __restrict__ x, const float* __restrict__ s,
                      ushortT* __restrict__ xpad) {
    __shared__ float tilef[64 * 129];   // [w 0..63][ch 0..127], 33 KB
    int bid = blockIdx.x;
    int cchunk = bid & 3;               // 4 chunks of 128 ch
    int rem = bid >> 2;
    int prow = rem % HP;
    int b = rem / HP;
    int tid = threadIdx.x;
    size_t rowbase = (((size_t)b * HP + prow) * HP) * CIN + cchunk * 128;
    if (prow == 0 || prow == HP - 1) {
        short8 z = {};
        for (int q = tid; q < HP * 16; q += 256) {   // 66 cols x 16 subs
            int col = q >> 4, sub = q & 15;
            *(short8*)(xpad + rowbase + (size_t)col * CIN + sub * 8) = z;
        }
        return;
    }
    int xr = prow - 1;
    int u = tid & 15;           // w quad
    int cbase = tid >> 4;       // 0..15
    #pragma unroll
    for (int it = 0; it < 8; ++it) {
        int c = cbase + it * 16;                     // 0..127
        int ch = cchunk * 128 + c;
        float4 v = *(const float4*)(x + (((size_t)b * CIN + ch) * HDIM + xr) * WDIM + u * 4);
        float sv = s[b * CIN + ch];
        tilef[(u * 4 + 0) * 129 + c] = v.x * sv;
        tilef[(u * 4 + 1) * 129 + c] = v.y * sv;
        tilef[(u * 4 + 2) * 129 + c] = v.z * sv;
        tilef[(u * 4 + 3) * 129 + c] = v.w * sv;
    }
    __syncthreads();
    #pragma unroll
    for (int it = 0; it < 4; ++it) {
        int q = it * 256 + tid;                      // 0..1023
        int col = 1 + (q >> 4);                      // 1..64
        int sub = q & 15;                            // ch octet
        const float* tr = tilef + (col - 1) * 129 + sub * 8;
        short8 o;
        #pragma unroll
        for (int r = 0; r < 8; ++r) o[r] = (short)f2bf(tr[r]);
        *(short8*)(xpad + rowbase + (size_t)col * CIN + sub * 8) = o;
    }
    if (tid < 32) {
        short8 z = {};
        int bcol = (tid < 16) ? 0 : (HP - 1);
        *(short8*)(xpad + rowbase + (size_t)bcol * CIN + (tid & 15) * 8) = z;
    }
}

// Implicit-GEMM conv, 256x256 tile, BK=64, double-buffered 128 KiB LDS,
// 8 waves (2m x 4n), per-wave 128x64. PROVEN R1/R4 phase structure (4 phases,
// double-barrier pacing, 8-slot XOR swizzle slot=sub^(row&7)) with ONE change:
// T4 counted vmcnt. Staging is ordered by when the next step READS each chunk:
//   ph0 issues [B0..B3, A0, A2]  (next-ph0 reads: B all rows + A rows 0-63,128-191)
//   ph1 issues [A1, A3]          (read only at next-ph1/ph3: A rows 64-127,192-255)
//   ph3 waits vmcnt(2)  -> A1,A3 stay in flight across the buffer swap
//   ph1 waits vmcnt(8)  -> drains the CURRENT step's A1,A3 just before DS_A(1,0)
// (R6 lesson: 2 blocks/CU is impossible at this tile — acc needs >128 VGPR;
//  launch_bounds(512,2) is mandatory. R5 lesson: only this swizzle is
//  conflict-free. R3 lesson: per-phase double barriers are load-bearing.)
#define MFMA_CLUSTER(MH) do { \
    __builtin_amdgcn_s_setprio(1); \
    _Pragma("unroll") for (int m_ = 0; m_ < 4; ++m_) { \
        _Pragma("unroll") for (int n_ = 0; n_ < 4; ++n_) \
            acc[(MH)*4 + m_][n_] = __builtin_amdgcn_mfma_f32_16x16x32_bf16( \
                af[m_], bf[n_], acc[(MH)*4 + m_][n_], 0, 0, 0); } \
    __builtin_amdgcn_s_setprio(0); \
} while (0)

#define DS_A(MH, KH) do { \
    _Pragma("unroll") for (int m_ = 0; m_ < 4; ++m_) { \
        int row_ = wave_m * 128 + (MH)*64 + m_*16 + l15; \
        af[m_] = *(const short8*)(Ar + row_*64 + ((((KH)*4 + quad) ^ (row_ & 7)) * 8)); \
    } } while (0)

#define DS_B(KH) do { \
    _Pragma("unroll") for (int n_ = 0; n_ < 4; ++n_) { \
        int row_ = wave_n * 64 + n_*16 + l15; \
        bf[n_] = *(const short8*)(Br + row_*64 + ((((KH)*4 + quad) ^ (row_ & 7)) * 8)); \
    } } while (0)

__global__ __launch_bounds__(512, 2) void k_conv(
    const ushortT* __restrict__ wbt, const ushortT* __restrict__ xpad,
    const float* __restrict__ dcoef, const float* __restrict__ bias,
    const float* __restrict__ noise, const float* __restrict__ nscp,
    float* __restrict__ out)
{
    extern __shared__ __align__(16) ushortT smem[];   // 131072 B
    // As buf0 @0, As buf1 @16384, Bs buf0 @32768, Bs buf1 @49152 (ushort units)

    int tid = threadIdx.x;
    int lane = tid & 63;
    int wave = tid >> 6;          // 0..7
    int wave_m = wave >> 2;       // 0..1  (128 couts each)
    int wave_n = wave & 3;        // 0..3  (64 pos each)
    int l15 = lane & 15;
    int quad = lane >> 4;

    // XCD-aware swizzle: nwg=512, 8 XCDs, 64 consecutive wgids per XCD.
    int bid = blockIdx.x;
    int wg = (bid & 7) * 64 + (bid >> 3);
    int mtile = wg >> 8;          // 0..1
    int ntile = wg & 255;         // 0..255
    int b = ntile >> 4;           // image
    int h0 = (ntile & 15) << 2;   // 4 output rows h0..h0+3
    int cout0 = mtile << 8;       // 256 couts

    // staging: per K-step, A tile = 256 rows x 64 ch x 2B = 2048 x 16B chunks,
    // 4 calls x 512 threads; same for B. chunk a: row=a>>3, slot=a&7,
    // global sub = slot ^ (row&7)  (involution with the DS_ read swizzle).
    unsigned aoff[4], boff[4], dstE[4];
    #pragma unroll
    for (int ca = 0; ca < 4; ++ca) {
        int a = ca * 512 + tid;
        int row = a >> 3;
        int sub = (a & 7) ^ (row & 7);
        aoff[ca] = (unsigned)((cout0 + row) * CIN + sub * 8);
        int prow = row >> 6;       // 0..3
        int pcol = row & 63;
        boff[ca] = (unsigned)((((b * HP) + h0 + prow) * HP + pcol) * CIN + sub * 8);
        dstE[ca] = (unsigned)(ca * 4096 + wave * 512);   // wave-uniform LDS base (elems)
    }

    f32x4 acc[8][4] = {};

    // ---- prologue: stage K-step 0 into buf0, full drain once
    {
        const ushortT* Asrc = wbt;        // t=0, cc=0
        const ushortT* Bsrc = xpad;       // tap offset 0
        #pragma unroll
        for (int ca = 0; ca < 4; ++ca) {
            gload16(Asrc + aoff[ca], smem + dstE[ca]);
            gload16(Bsrc + boff[ca], smem + 32768 + dstE[ca]);
        }
        asm volatile("s_waitcnt vmcnt(0)" ::: "memory");
        __builtin_amdgcn_s_barrier();
    }

    // ---- main loop: 72 K-steps (9 taps x 8 chunks of 64 ch)
    #pragma unroll 2
    for (int ks = 0; ks < 72; ++ks) {
        int cur = ks & 1;
        const ushortT* Ar = smem + cur * 16384;
        const ushortT* Br = smem + 32768 + cur * 16384;
        ushortT* Aw = smem + (cur ^ 1) * 16384;
        ushortT* Bw = smem + 32768 + (cur ^ 1) * 16384;
        int ksn = ks + 1;
        bool st = ksn < 72;
        int tn = ksn >> 3, ccn = ksn & 7;
        const ushortT* Asrc = wbt + tn * (COUTC * CIN) + ccn * 64;
        const ushortT* Bsrc = xpad + ((tn / 3) * HP + (tn % 3)) * CIN + ccn * 64;

        short8 af[4], bf[4];

        // ---- phase 0: kh=0, mh=0 ; stage B0..B3, A0, A2 (read at next-ph0)
        if (st) {
            gload16(Bsrc + boff[0], Bw + dstE[0]); gload16(Bsrc + boff[1], Bw + dstE[1]);
            gload16(Bsrc + boff[2], Bw + dstE[2]); gload16(Bsrc + boff[3], Bw + dstE[3]);
            gload16(Asrc + aoff[0], Aw + dstE[0]); gload16(Asrc + aoff[2], Aw + dstE[2]);
        }
        DS_B(0);
        DS_A(0, 0);
        __builtin_amdgcn_s_barrier();
        asm volatile("s_waitcnt lgkmcnt(0)");
        MFMA_CLUSTER(0);
        __builtin_amdgcn_s_barrier();

        // ---- phase 1: kh=0, mh=1 ; stage A1, A3 (read at next-ph1/ph3);
        //      counted guard: drain THIS step's A1,A3 before reading their rows
        if (st) {
            gload16(Asrc + aoff[1], Aw + dstE[1]); gload16(Asrc + aoff[3], Aw + dstE[3]);
            asm volatile("s_waitcnt vmcnt(8)" ::: "memory");
        } else {
            asm volatile("s_waitcnt vmcnt(0)" ::: "memory");
        }
        DS_A(1, 0);
        __builtin_amdgcn_s_barrier();
        asm volatile("s_waitcnt lgkmcnt(0)");
        MFMA_CLUSTER(1);
        __builtin_amdgcn_s_barrier();

        // ---- phase 2: kh=1, mh=0
        DS_B(1);
        DS_A(0, 1);
        __builtin_amdgcn_s_barrier();
        asm volatile("s_waitcnt lgkmcnt(0)");
        MFMA_CLUSTER(0);
        __builtin_amdgcn_s_barrier();

        // ---- phase 3: kh=1, mh=1 ; counted drain: B+A0+A2 of next step ready,
        //      A1,A3 stay in flight across the swap (drained at next ph1)
        DS_A(1, 1);
        __builtin_amdgcn_s_barrier();
        asm volatile("s_waitcnt lgkmcnt(0)");
        MFMA_CLUSTER(1);
        if (st) asm volatile("s_waitcnt vmcnt(2)" ::: "memory");
        __builtin_amdgcn_s_barrier();
    }

    // ---- epilogue: out = acc * d[b,o] + noise*nscale + bias
    float ns = nscp[0];
    int col = lane & 15, rq = lane >> 4;
    #pragma unroll
    for (int nj = 0; nj < 4; ++nj) {
        int pos = wave_n * 64 + nj * 16 + col;
        int hh = h0 + (pos >> 6), ww = pos & 63;
        float nz = noise[((size_t)b << 12) + (hh << 6) + ww] * ns;
        #pragma unroll
        for (int mi = 0; mi < 8; ++mi) {
            int coutb = cout0 + wave_m * 128 + mi * 16 + rq * 4;
            f32x4 dv = *(const f32x4*)(dcoef + b * COUTC + coutb);
            f32x4 bv = *(const f32x4*)(bias + coutb);
            f32x4 a = acc[mi][nj];
            #pragma unroll
            for (int r = 0; r < 4; ++r) {
                out[(((size_t)(b * COUTC + coutb + r)) << 12) + (hh << 6) + ww]
                    = a[r] * dv[r] + nz + bv[r];
            }
        }
    }
}

extern "C" void kernel_launch(void* const* d_in, const int* in_sizes, int n_in,
                              void* d_out, int out_size, void* d_ws, size_t ws_size,
                              hipStream_t stream) {
    const float* x      = (const float*)d_in[0];
    const float* y      = (const float*)d_in[1];
    const float* noise  = (const float*)d_in[2];
    const float* weight = (const float*)d_in[3];
    const float* bias   = (const float*)d_in[4];
    const float* mod_w  = (const float*)d_in[5];
    const float* mod_b  = (const float*)d_in[6];
    const float* nsc    = (const float*)d_in[7];
    float* out = (float*)d_out;

    char* ws = (char*)d_ws;
    float*   s     = (float*)(ws);
    float*   dcoef = (float*)(ws + 32768);
    float*   w2    = (float*)(ws + 65536);
    ushortT* wbt   = (ushortT*)(ws + 1114112);
    ushortT* xpad  = (ushortT*)(ws + 5832704);

    static bool attr_done = false;
    if (!attr_done) {
        (void)hipFuncSetAttribute(reinterpret_cast<const void*>(k_conv),
                                  hipFuncAttributeMaxDynamicSharedMemorySize, 131072);
        attr_done = true;
    }

    k_style<<<dim3(2048), dim3(256), 0, stream>>>(y, mod_w, mod_b, s);
    k_prepw<<<dim3(1024), dim3(256), 0, stream>>>(weight, w2, wbt);
    k_demod<<<dim3(2048), dim3(256), 0, stream>>>(w2, s, dcoef);
    k_pad<<<dim3(BATCH * HP * 4), dim3(256), 0, stream>>>(x, s, xpad);
    k_conv<<<dim3(512), dim3(512), 131072, stream>>>(wbt, xpad, dcoef, bias, noise, nsc, out);
}

// Round 10
// 503.153 us; speedup vs baseline: 4.9160x; 1.0153x over previous
//
#include <hip/hip_runtime.h>
#include <hip/hip_bf16.h>

typedef unsigned short ushortT;
typedef __attribute__((ext_vector_type(8))) short short8;
typedef __attribute__((ext_vector_type(4))) float f32x4;

#define CIN 512
#define COUTC 512
#define HIDC 512
#define BATCH 16
#define HDIM 64
#define WDIM 64
#define HP 66   // padded spatial

// ws layout (bytes):
//   s     @ 0        : 16*512*4   = 32768
//   d     @ 32768    : 16*512*4   = 32768
//   w2    @ 65536    : 512*512*4  = 1048576
//   wbt   @ 1114112  : 9*512*512*2 = 4718592   (bf16, tap-major [t][o][i])
//   xpad  @ 5832704  : 16*66*66*512*2 = 71368704 (bf16 NHWC, zero-padded)

__device__ __forceinline__ unsigned short f2bf(float f) {
    __hip_bfloat16 h = __float2bfloat16(f);
    return __builtin_bit_cast(unsigned short, h);
}

__device__ __forceinline__ void gload16(const ushortT* g, ushortT* l) {
    __builtin_amdgcn_global_load_lds(
        (const __attribute__((address_space(1))) void*)g,
        (__attribute__((address_space(3))) void*)l, 16, 0, 0);
}

// s[b][i] = (y[b,:] . mod_w[i,:]) / sqrt(512) + mod_b[i] + 1   — one wave per (b,i)
__global__ void k_style(const float* __restrict__ y, const float* __restrict__ mw,
                        const float* __restrict__ mb, float* __restrict__ s) {
    int lane = threadIdx.x & 63;
    int wid = blockIdx.x * 4 + (threadIdx.x >> 6);   // 0..8191
    int b = wid >> 9, i = wid & 511;
    int h0 = lane * 8;
    float4 ya = *(const float4*)(y + b * HIDC + h0);
    float4 yb = *(const float4*)(y + b * HIDC + h0 + 4);
    float4 wa = *(const float4*)(mw + (size_t)i * HIDC + h0);
    float4 wb = *(const float4*)(mw + (size_t)i * HIDC + h0 + 4);
    float v = ya.x*wa.x + ya.y*wa.y + ya.z*wa.z + ya.w*wa.w
            + yb.x*wb.x + yb.y*wb.y + yb.z*wb.z + yb.w*wb.w;
    #pragma unroll
    for (int off = 32; off > 0; off >>= 1) v += __shfl_down(v, off);
    if (lane == 0) s[wid] = v * 0.04419417382415922f + mb[i] + 1.0f;
}

// wbt[k][o][i] = bf16(w[o][i][k] * coef);  w2[o][i] = sum_k (w*coef)^2
__global__ void k_prepw(const float* __restrict__ w, float* __restrict__ w2,
                        ushortT* __restrict__ wbt) {
    int t = blockIdx.x * 256 + threadIdx.x;   // o*512 + i
    const float* wp = w + (size_t)t * 9;
    const float coef = 0.014731391274719739f; // 1/sqrt(4608)
    float sum = 0.f;
    #pragma unroll
    for (int k = 0; k < 9; ++k) {
        float v = wp[k] * coef;
        sum += v * v;
        wbt[(size_t)k * (COUTC * CIN) + t] = f2bf(v);
    }
    w2[t] = sum;
}

// d[b][o] = rsqrt(sum_i w2[o][i] * s[b][i]^2 + 1e-8)  — one wave per (b,o)
__global__ void k_demod(const float* __restrict__ w2, const float* __restrict__ s,
                        float* __restrict__ d) {
    int lane = threadIdx.x & 63;
    int wid = blockIdx.x * 4 + (threadIdx.x >> 6);   // 0..8191
    int b = wid >> 9, o = wid & 511;
    int i0 = lane * 8;
    float4 wa = *(const float4*)(w2 + (size_t)o * CIN + i0);
    float4 wb = *(const float4*)(w2 + (size_t)o * CIN + i0 + 4);
    float4 sa = *(const float4*)(s + b * CIN + i0);
    float4 sb = *(const float4*)(s + b * CIN + i0 + 4);
    float v = wa.x*sa.x*sa.x + wa.y*sa.y*sa.y + wa.z*sa.z*sa.z + wa.w*sa.w*sa.w
            + wb.x*sb.x*sb.x + wb.y*sb.y*sb.y + wb.z*sb.z*sb.z + wb.w*sb.w*sb.w;
    #pragma unroll
    for (int off = 32; off > 0; off >>= 1) v += __shfl_down(v, off);
    if (lane == 0) d[wid] = rsqrtf(v + 1e-8f);
}

// xpad[b][row][col][ch] = bf16(x[b][ch][row-1][col-1] * s[b][ch]), zero border.
__global__ void k_pad(const float* __restrict__ x, const float* __restrict__ s,
                      ushortT* __restrict__ xpad) {
    __shared__ float tilef[64 * 129];   // [w 0..63][ch 0..127], 33 KB
    int bid = blockIdx.x;
    int cchunk = bid & 3;               // 4 chunks of 128 ch
    int rem = bid >> 2;
    int prow = rem % HP;
    int b = rem / HP;
    int tid = threadIdx.x;
    size_t rowbase = (((size_t)b * HP + prow) * HP) * CIN + cchunk * 128;
    if (prow == 0 || prow == HP - 1) {
        short8 z = {};
        for (int q = tid; q < HP * 16; q += 256) {   // 66 cols x 16 subs
            int col = q >> 4, sub = q & 15;
            *(short8*)(xpad + rowbase + (size_t)col * CIN + sub * 8) = z;
        }
        return;
    }
    int xr = prow - 1;
    int u = tid & 15;           // w quad
    int cbase = tid >> 4;       // 0..15
    #pragma unroll
    for (int it = 0; it < 8; ++it) {
        int c = cbase + it * 16;                     // 0..127
        int ch = cchunk * 128 + c;
        float4 v = *(const float4*)(x + (((size_t)b * CIN + ch) * HDIM + xr) * WDIM + u * 4);
        float sv = s[b * CIN + ch];
        tilef[(u * 4 + 0) * 129 + c] = v.x * sv;
        tilef[(u * 4 + 1) * 129 + c] = v.y * sv;
        tilef[(u * 4 + 2) * 129 + c] = v.z * sv;
        tilef[(u * 4 + 3) * 129 + c] = v.w * sv;
    }
    __syncthreads();
    #pragma unroll
    for (int it = 0; it < 4; ++it) {
        int q = it * 256 + tid;                      // 0..1023
        int col = 1 + (q >> 4);                      // 1..64
        int sub = q & 15;                            // ch octet
        const float* tr = tilef + (col - 1) * 129 + sub * 8;
        short8 o;
        #pragma unroll
        for (int r = 0; r < 8; ++r) o[r] = (short)f2bf(tr[r]);
        *(short8*)(xpad + rowbase + (size_t)col * CIN + sub * 8) = o;
    }
    if (tid < 32) {
        short8 z = {};
        int bcol = (tid < 16) ? 0 : (HP - 1);
        *(short8*)(xpad + rowbase + (size_t)bcol * CIN + (tid & 15) * 8) = z;
    }
}

// Implicit-GEMM conv, 256x256 tile, BK=64, chunk-major/tap-minor K-order with a
// PER-CHUNK B-STRIP: the 6x66-row xpad window (50.7 KB) is staged ONCE per
// 64-ch chunk and all 9 taps ds_read shifted rows of it (B staging 72->8
// stages/block, 5.5x less; A stays per-step double-buffered).
// Proven pieces kept verbatim: 8-slot XOR swizzle slot=sub^(row&7) on both
// tiles, 4-phase double-barrier pacing (R3: load-bearing), fragment geometry,
// epilogue. Phases = (kh0,mh0)(kh1,mh0)(kh0,mh1)(kh1,mh1) with TWO B-reg sets
// (bfA=kh0, bfB=kh1) so all strip reads finish by phase B; next strip is
// staged at phase-C top (2 phases of latency cover before first read).
// (R6: >1 block/CU impossible — acc alone = 128 VGPR; R5: only this swizzle
//  is conflict-free; R7: counted vmcnt neutral -> drain not critical.)
#define CLUST(A_, B_, MH) do { \
    __builtin_amdgcn_s_setprio(1); \
    _Pragma("unroll") for (int m_ = 0; m_ < 4; ++m_) { \
        _Pragma("unroll") for (int n_ = 0; n_ < 4; ++n_) \
            acc[(MH)*4 + m_][n_] = __builtin_amdgcn_mfma_f32_16x16x32_bf16( \
                A_[m_], B_[n_], acc[(MH)*4 + m_][n_], 0, 0, 0); } \
    __builtin_amdgcn_s_setprio(0); \
} while (0)

#define RD_A(MH, KH) do { \
    _Pragma("unroll") for (int m_ = 0; m_ < 4; ++m_) { \
        int row_ = wave_m * 128 + (MH)*64 + m_*16 + l15; \
        af[m_] = *(const short8*)(Ar + row_*64 + ((((KH)*4 + quad) ^ (row_ & 7)) * 8)); \
    } } while (0)

#define RD_B(dst, KH) do { \
    _Pragma("unroll") for (int n_ = 0; n_ < 4; ++n_) { \
        int r_ = rbase[n_] + ty * 66 + tx; \
        dst[n_] = *(const short8*)(Bs + r_*64 + ((((KH)*4 + quad) ^ (r_ & 7)) * 8)); \
    } } while (0)

__global__ __launch_bounds__(512, 2) void k_conv(
    const ushortT* __restrict__ wbt, const ushortT* __restrict__ xpad,
    const float* __restrict__ dcoef, const float* __restrict__ bias,
    const float* __restrict__ noise, const float* __restrict__ nscp,
    float* __restrict__ out)
{
    extern __shared__ __align__(16) ushortT smem[];   // 122880 B
    // A buf0 @0, A buf1 @16384, B strip @32768 (28672 ushorts = 448 rows x 64ch)

    int tid = threadIdx.x;
    int lane = tid & 63;
    int wave = tid >> 6;          // 0..7
    int wave_m = wave >> 2;       // 0..1  (128 couts each)
    int wave_n = wave & 3;        // 0..3  (64 pos each)
    int l15 = lane & 15;
    int quad = lane >> 4;

    // XCD-aware swizzle: nwg=512, 8 XCDs, 64 consecutive wgids per XCD.
    int bid = blockIdx.x;
    int wg = (bid & 7) * 64 + (bid >> 3);
    int mtile = wg >> 8;          // 0..1
    int ntile = wg & 255;         // 0..255
    int b = ntile >> 4;           // image
    int h0 = (ntile & 15) << 2;   // 4 output rows h0..h0+3
    int cout0 = mtile << 8;       // 256 couts

    // A staging: 2048 x 16B chunks, 4 calls x 512 threads. chunk a: row=a>>3,
    // slot=a&7, global sub = slot ^ (row&7)  (involution with RD_A swizzle).
    unsigned aoff[4], dstE[4];
    #pragma unroll
    for (int ca = 0; ca < 4; ++ca) {
        int a = ca * 512 + tid;
        int row = a >> 3;
        int sub = (a & 7) ^ (row & 7);
        aoff[ca] = (unsigned)((cout0 + row) * CIN + sub * 8);
        dstE[ca] = (unsigned)(ca * 4096 + wave * 512);   // wave-uniform LDS base
    }
    // B strip staging: rows r = srow*66+scol (6 x 66 = 396 real rows, padded to
    // 448), 3584 chunks = 7 calls x 512 threads; r clamped -> pad rows hold
    // duplicate data, never read. Source is 128B-contiguous per row.
    unsigned soff[7];
    #pragma unroll
    for (int sc = 0; sc < 7; ++sc) {
        int a = sc * 512 + tid;
        int r = a >> 3; if (r > 395) r = 395;
        int sub = (a & 7) ^ (r & 7);
        int srow = r / 66, scol = r - srow * 66;
        soff[sc] = (unsigned)((((b * HP) + h0 + srow) * HP + scol) * CIN + sub * 8);
    }
    // B fragment row bases: pos = wave_n*64 + nj*16 + l15 -> strip row prow*66+pcol
    int rbase[4];
    #pragma unroll
    for (int nj = 0; nj < 4; ++nj) {
        int pos = wave_n * 64 + nj * 16 + l15;
        rbase[nj] = (pos >> 6) * 66 + (pos & 63);
    }

    ushortT* Bs = smem + 32768;
    f32x4 acc[8][4] = {};

    // ---- prologue: strip(cc=0) + A(t=0,cc=0) into buf0, full drain once
    #pragma unroll
    for (int sc = 0; sc < 7; ++sc)
        gload16(xpad + soff[sc], Bs + (unsigned)(sc * 4096 + wave * 512));
    #pragma unroll
    for (int ca = 0; ca < 4; ++ca)
        gload16(wbt + aoff[ca], smem + dstE[ca]);
    asm volatile("s_waitcnt vmcnt(0)" ::: "memory");
    __builtin_amdgcn_s_barrier();

    // ---- main loop: 8 chunks x 9 taps = 72 K-steps
    int cur = 0;
    for (int cc = 0; cc < 8; ++cc) {
        for (int t = 0; t < 9; ++t) {
            const ushortT* Ar = smem + cur * 16384;
            ushortT* Aw = smem + (cur ^ 1) * 16384;
            bool st = !(cc == 7 && t == 8);
            int tn = (t < 8) ? t + 1 : 0;
            int ccn = (t < 8) ? cc : cc + 1;
            const ushortT* Asrc = wbt + (size_t)tn * (COUTC * CIN) + ccn * 64;
            int ty = t / 3, tx = t - ty * 3;

            short8 af[4], bfA[4], bfB[4];

            // phA: stage A(next step); read B(kh0)->bfA + A(0,0); MFMA mh0
            if (st) {
                gload16(Asrc + aoff[0], Aw + dstE[0]);
                gload16(Asrc + aoff[1], Aw + dstE[1]);
                gload16(Asrc + aoff[2], Aw + dstE[2]);
                gload16(Asrc + aoff[3], Aw + dstE[3]);
            }
            RD_B(bfA, 0);
            RD_A(0, 0);
            __builtin_amdgcn_s_barrier();
            asm volatile("s_waitcnt lgkmcnt(0)");
            CLUST(af, bfA, 0);
            __builtin_amdgcn_s_barrier();

            // phB: read B(kh1)->bfB + A(0,1); MFMA mh0  (all strip reads done after this)
            RD_B(bfB, 1);
            RD_A(0, 1);
            __builtin_amdgcn_s_barrier();
            asm volatile("s_waitcnt lgkmcnt(0)");
            CLUST(af, bfB, 0);
            __builtin_amdgcn_s_barrier();

            // phC: stage next strip (last tap of chunk; strip reads all drained);
            //      read A(1,0); MFMA mh1 with bfA (registers)
            if (t == 8 && cc < 7) {
                const ushortT* Ssrc = xpad + (cc + 1) * 64;
                #pragma unroll
                for (int sc = 0; sc < 7; ++sc)
                    gload16(Ssrc + soff[sc], Bs + (unsigned)(sc * 4096 + wave * 512));
            }
            RD_A(1, 0);
            __builtin_amdgcn_s_barrier();
            asm volatile("s_waitcnt lgkmcnt(0)");
            CLUST(af, bfA, 1);
            __builtin_amdgcn_s_barrier();

            // phD: read A(1,1); MFMA mh1 with bfB; drain staging before swap
            RD_A(1, 1);
            __builtin_amdgcn_s_barrier();
            asm volatile("s_waitcnt lgkmcnt(0)");
            CLUST(af, bfB, 1);
            if (st) asm volatile("s_waitcnt vmcnt(0)" ::: "memory");
            __builtin_amdgcn_s_barrier();

            cur ^= 1;
        }
    }

    // ---- epilogue: out = acc * d[b,o] + noise*nscale + bias
    float ns = nscp[0];
    int col = lane & 15, rq = lane >> 4;
    #pragma unroll
    for (int nj = 0; nj < 4; ++nj) {
        int pos = wave_n * 64 + nj * 16 + col;
        int hh = h0 + (pos >> 6), ww = pos & 63;
        float nz = noise[((size_t)b << 12) + (hh << 6) + ww] * ns;
        #pragma unroll
        for (int mi = 0; mi < 8; ++mi) {
            int coutb = cout0 + wave_m * 128 + mi * 16 + rq * 4;
            f32x4 dv = *(const f32x4*)(dcoef + b * COUTC + coutb);
            f32x4 bv = *(const f32x4*)(bias + coutb);
            f32x4 a = acc[mi][nj];
            #pragma unroll
            for (int r = 0; r < 4; ++r) {
                out[(((size_t)(b * COUTC + coutb + r)) << 12) + (hh << 6) + ww]
                    = a[r] * dv[r] + nz + bv[r];
            }
        }
    }
}

extern "C" void kernel_launch(void* const* d_in, const int* in_sizes, int n_in,
                              void* d_out, int out_size, void* d_ws, size_t ws_size,
                              hipStream_t stream) {
    const float* x      = (const float*)d_in[0];
    const float* y      = (const float*)d_in[1];
    const float* noise  = (const float*)d_in[2];
    const float* weight = (const float*)d_in[3];
    const float* bias   = (const float*)d_in[4];
    const float* mod_w  = (const float*)d_in[5];
    const float* mod_b  = (const float*)d_in[6];
    const float* nsc    = (const float*)d_in[7];
    float* out = (float*)d_out;

    char* ws = (char*)d_ws;
    float*   s     = (float*)(ws);
    float*   dcoef = (float*)(ws + 32768);
    float*   w2    = (float*)(ws + 65536);
    ushortT* wbt   = (ushortT*)(ws + 1114112);
    ushortT* xpad  = (ushortT*)(ws + 5832704);

    static bool attr_done = false;
    if (!attr_done) {
        (void)hipFuncSetAttribute(reinterpret_cast<const void*>(k_conv),
                                  hipFuncAttributeMaxDynamicSharedMemorySize, 122880);
        attr_done = true;
    }

    k_style<<<dim3(2048), dim3(256), 0, stream>>>(y, mod_w, mod_b, s);
    k_prepw<<<dim3(1024), dim3(256), 0, stream>>>(weight, w2, wbt);
    k_demod<<<dim3(2048), dim3(256), 0, stream>>>(w2, s, dcoef);
    k_pad<<<dim3(BATCH * HP * 4), dim3(256), 0, stream>>>(x, s, xpad);
    k_conv<<<dim3(512), dim3(512), 122880, stream>>>(wbt, xpad, dcoef, bias, noise, nsc, out);
}